// Round 11
// baseline (123.074 us; speedup 1.0000x reference)
//
#include <hip/hip_runtime.h>
#include <hip/hip_bf16.h>

typedef __attribute__((ext_vector_type(8))) short short8;
typedef __attribute__((ext_vector_type(4))) float f32x4;
typedef __attribute__((ext_vector_type(4))) float fv4;
typedef __attribute__((ext_vector_type(4))) unsigned int u32x4;

#define MFMA16(a, b, c) __builtin_amdgcn_mfma_f32_16x16x32_bf16((a), (b), (c), 0, 0, 0)

typedef const __attribute__((address_space(1))) unsigned int gu32;
typedef __attribute__((address_space(3))) unsigned int lu32;

// float -> bf16 RNE (inputs are finite; no NaN handling needed)
__device__ __forceinline__ short f2b(float f) {
  unsigned int x = __builtin_bit_cast(unsigned int, f);
  x += 0x7fffu + ((x >> 16) & 1u);
  return (short)(x >> 16);
}

// packed f32x2 -> bf16x2 (RNE) in one instruction; D.lo = S0, D.hi = S1
__device__ __forceinline__ unsigned int cvtpk(float lo, float hi) {
  unsigned int r;
  asm("v_cvt_pk_bf16_f32 %0, %1, %2" : "=v"(r) : "v"(lo), "v"(hi));
  return r;
}

// hardware 2^x as a compiler-known instruction (TRANS hazards handled)
#define hexp2(x) __builtin_amdgcn_exp2f(x)

// ===================== weight prep =====================
// WqT/WkT/WvT: [512][1024] bf16, WT[n][d] = W[n>>5][d][n&31]  (B^T layout)
// Wq additionally scaled by d_model^-0.5 * log2(e) so QK^T logits are base-2.
// WoT: [1024][512] bf16, WoT[n][k] = Wo[k][n]
__global__ void prep_weights(const float* __restrict__ Wq, const float* __restrict__ Wk,
                             const float* __restrict__ Wv, const float* __restrict__ Wo,
                             short* __restrict__ WqT, short* __restrict__ WkT,
                             short* __restrict__ WvT, short* __restrict__ WoT) {
  const float SC2 = 0.045084220027780106f;  // (1/32) * log2(e)
  int idx = blockIdx.x * 256 + threadIdx.x;
  if (idx < 3 * 512 * 1024) {
    int wsel = idx >> 19;
    int rem = idx & ((1 << 19) - 1);
    int n = rem >> 10;
    int d = rem & 1023;
    const float* W = (wsel == 0) ? Wq : ((wsel == 1) ? Wk : Wv);
    short* WT = (wsel == 0) ? WqT : ((wsel == 1) ? WkT : WvT);
    float v = W[(n >> 5) * (1024 * 32) + d * 32 + (n & 31)];
    if (wsel == 0) v *= SC2;
    WT[n * 1024 + d] = f2b(v);
  } else {
    int idx2 = idx - 3 * 512 * 1024;
    int n = idx2 >> 9;
    int kk = idx2 & 511;
    WoT[n * 512 + kk] = f2b(Wo[kk * 1024 + n]);
  }
}

// ===================== projection GEMM (gl_lds staged) =====================
// C[M,N] = A[M,K=1024] * BT[N,K]^T, 128x128 tile, BK=64, 4 waves (2x2).
// A (f32) and B (bf16) staged via 16B global_load_lds — no VGPR round-trip,
// the compiler cannot sink the staging (R6/R10 showed reg-staging collapses
// to VGPR=56 with serialized chunks). LDS rows hold 16B chunks XOR-swizzled
// by u' = u ^ (row&7) applied to BOTH the per-lane staged global source and
// the ds_read address (involution) -> conflict-free quarter-wave reads.
// A converted f32->bf16 at fragment read (cvtpk; VALU was 9% idle).
// Grid 768 = 256 CU x 3 blocks (launch_bounds(256,3)) — zero tail.
// 1D id = bm + 64*(bn+4z): id%8==bm%8 pins each A row-panel to one XCD.
__global__ __launch_bounds__(256, 3) void proj_gemm(
    const float* __restrict__ q, const float* __restrict__ k, const float* __restrict__ v,
    const short* __restrict__ WqT, const short* __restrict__ WkT, const short* __restrict__ WvT,
    short* __restrict__ Qb, short* __restrict__ Kb, short* __restrict__ Vtb) {
  __shared__ char smem[49152];  // A f32 [128][64] @0 (32KB) + B bf16 [128][64] @32768
  const int tid = threadIdx.x;
  const int lane = tid & 63;
  const int w = tid >> 6;
  const int l15 = lane & 15, g = lane >> 4;
  const int wm = (w >> 1) * 64, wn = (w & 1) * 64;
  const int id = blockIdx.x;
  const int bm = id & 63;
  const int r = id >> 6;
  const int bn = r & 3;
  const int z = r >> 2;
  const float* A = (z == 0) ? q : ((z == 1) ? k : v);
  const short* BT = (z == 0) ? WqT : ((z == 1) ? WkT : WvT);
  const int bm0 = bm * 128, bn0 = bn * 128;

  // staging lane constants
  const int arow = lane >> 4;   // A: 4 rows per instr
  const int au = lane & 15;     // A: 16B subslot in 256B row
  const int brow = lane >> 3;   // B: 8 rows per instr
  const int bu = lane & 7;      // B: 16B slot in 128B row

  f32x4 zf = {0.f, 0.f, 0.f, 0.f};
  f32x4 acc[4][4];
#pragma unroll
  for (int a = 0; a < 4; ++a)
#pragma unroll
    for (int bq = 0; bq < 4; ++bq) acc[a][bq] = zf;

  for (int k0 = 0; k0 < 1024; k0 += 64) {
    // ---- stage A: 8 instrs x (4 rows x 256B); swizzled global source ----
#pragma unroll
    for (int i = 0; i < 8; ++i) {
      int row = 32 * w + 4 * i + arow;
      int u = au ^ (row & 7);
      __builtin_amdgcn_global_load_lds(
          (gu32*)(A + (size_t)(bm0 + row) * 1024 + k0 + 4 * u),
          (lu32*)(smem + w * 8192 + i * 1024), 16, 0, 0);
    }
    // ---- stage B: 4 instrs x (8 rows x 128B) ----
#pragma unroll
    for (int i = 0; i < 4; ++i) {
      int row = 32 * w + 8 * i + brow;
      int u = bu ^ (row & 7);
      __builtin_amdgcn_global_load_lds(
          (gu32*)(BT + (size_t)(bn0 + row) * 1024 + k0 + 8 * u),
          (lu32*)(smem + 32768 + w * 4096 + i * 1024), 16, 0, 0);
    }
    __syncthreads();  // drains vmcnt: tiles ready

#pragma unroll
    for (int kk = 0; kk < 2; ++kk) {
      short8 af[4], bfr[4];
#pragma unroll
      for (int mf = 0; mf < 4; ++mf) {
        int row = wm + mf * 16 + l15;
        int u0 = 8 * kk + 2 * g;
        fv4 a0 = *(const fv4*)(smem + row * 256 + ((u0 ^ (row & 7)) * 16));
        fv4 a1 = *(const fv4*)(smem + row * 256 + (((u0 + 1) ^ (row & 7)) * 16));
        u32x4 wv;
        wv[0] = cvtpk(a0[0], a0[1]);
        wv[1] = cvtpk(a0[2], a0[3]);
        wv[2] = cvtpk(a1[0], a1[1]);
        wv[3] = cvtpk(a1[2], a1[3]);
        af[mf] = __builtin_bit_cast(short8, wv);
      }
#pragma unroll
      for (int nf = 0; nf < 4; ++nf) {
        int row = wn + nf * 16 + l15;
        int c = 4 * kk + g;
        bfr[nf] = *(const short8*)(smem + 32768 + row * 128 + ((c ^ (row & 7)) * 16));
      }
#pragma unroll
      for (int mf = 0; mf < 4; ++mf)
#pragma unroll
        for (int nf = 0; nf < 4; ++nf)
          acc[mf][nf] = MFMA16(af[mf], bfr[nf], acc[mf][nf]);
    }
    __syncthreads();  // compute done before next stage overwrites
  }

#pragma unroll
  for (int mf = 0; mf < 4; ++mf)
#pragma unroll
    for (int nf = 0; nf < 4; ++nf)
#pragma unroll
      for (int i = 0; i < 4; ++i) {
        int row = bm0 + wm + mf * 16 + g * 4 + i;  // m index (b*2048+s)
        int col = bn0 + wn + nf * 16 + l15;        // n index (h*32+e)
        int bb = row >> 11, ss = row & 2047;
        int hh = col >> 5, ee = col & 31;
        short val = f2b(acc[mf][nf][i]);
        if (z == 2)
          Vtb[((size_t)(bb * 16 + hh) * 32 + ee) * 2048 + ss] = val;
        else if (z == 1)
          Kb[((size_t)(bb * 16 + hh) * 2048 + ss) * 32 + ee] = val;
        else
          Qb[((size_t)(bb * 16 + hh) * 2048 + ss) * 32 + ee] = val;
      }
}

// ===================== output GEMM (gl_lds staged) =====================
// C[8192,1024] = X[8192,512] * WoT[1024,512]^T. Both operands bf16: pure
// gl_lds staging, same swizzle as proj. Grid 512 = 256 CU x 2 — zero tail.
__global__ __launch_bounds__(256, 2) void out_gemm(const short* __restrict__ X,
                                                   const short* __restrict__ WoT,
                                                   float* __restrict__ out) {
  __shared__ char smem[32768];  // A bf16 [128][64] @0 + B bf16 [128][64] @16384
  const int tid = threadIdx.x;
  const int lane = tid & 63;
  const int w = tid >> 6;
  const int l15 = lane & 15, g = lane >> 4;
  const int wm = (w >> 1) * 64, wn = (w & 1) * 64;
  const int id = blockIdx.x;
  const int bm0 = (id & 63) * 128, bn0 = (id >> 6) * 128;

  const int brow = lane >> 3;
  const int bu = lane & 7;

  f32x4 zf = {0.f, 0.f, 0.f, 0.f};
  f32x4 acc[4][4];
#pragma unroll
  for (int a = 0; a < 4; ++a)
#pragma unroll
    for (int bq = 0; bq < 4; ++bq) acc[a][bq] = zf;

  for (int k0 = 0; k0 < 512; k0 += 64) {
#pragma unroll
    for (int i = 0; i < 4; ++i) {
      int row = 32 * w + 8 * i + brow;
      int u = bu ^ (row & 7);
      __builtin_amdgcn_global_load_lds(
          (gu32*)(X + (size_t)(bm0 + row) * 512 + k0 + 8 * u),
          (lu32*)(smem + w * 4096 + i * 1024), 16, 0, 0);
      __builtin_amdgcn_global_load_lds(
          (gu32*)(WoT + (size_t)(bn0 + row) * 512 + k0 + 8 * u),
          (lu32*)(smem + 16384 + w * 4096 + i * 1024), 16, 0, 0);
    }
    __syncthreads();

#pragma unroll
    for (int kk = 0; kk < 2; ++kk) {
      short8 af[4], bfr[4];
#pragma unroll
      for (int mf = 0; mf < 4; ++mf) {
        int row = wm + mf * 16 + l15;
        int c = 4 * kk + g;
        af[mf] = *(const short8*)(smem + row * 128 + ((c ^ (row & 7)) * 16));
      }
#pragma unroll
      for (int nf = 0; nf < 4; ++nf) {
        int row = wn + nf * 16 + l15;
        int c = 4 * kk + g;
        bfr[nf] = *(const short8*)(smem + 16384 + row * 128 + ((c ^ (row & 7)) * 16));
      }
#pragma unroll
      for (int mf = 0; mf < 4; ++mf)
#pragma unroll
        for (int nf = 0; nf < 4; ++nf)
          acc[mf][nf] = MFMA16(af[mf], bfr[nf], acc[mf][nf]);
    }
    __syncthreads();
  }

#pragma unroll
  for (int mf = 0; mf < 4; ++mf)
#pragma unroll
    for (int nf = 0; nf < 4; ++nf)
#pragma unroll
      for (int i = 0; i < 4; ++i) {
        int row = bm0 + wm + mf * 16 + g * 4 + i;
        int col = bn0 + wn + nf * 16 + l15;
        out[(size_t)row * 1024 + col] = acc[mf][nf][i];
      }
}

// ===================== fused flash attention =====================
// (unchanged from R9 — LDS-staged K/V via gl_lds, swapped QK^T, permuted
// K rows, no online max, ones-MFMA denominator, head-pinned XCD grid)
__device__ __forceinline__ void qk_half(short8 k0, short8 k1, short8 k2, short8 k3,
                                        short8 qf, const f32x4& zf,
                                        short8& pf0, short8& pf1) {
  f32x4 s0 = MFMA16(k0, qf, zf);
  f32x4 s1 = MFMA16(k1, qf, zf);
  f32x4 s2 = MFMA16(k2, qf, zf);
  f32x4 s3 = MFMA16(k3, qf, zf);
#pragma unroll
  for (int i = 0; i < 4; ++i) {
    s0[i] = hexp2(s0[i]);
    s1[i] = hexp2(s1[i]);
    s2[i] = hexp2(s2[i]);
    s3[i] = hexp2(s3[i]);
  }
  u32x4 w0, w1;
  w0[0] = cvtpk(s0[0], s0[1]);
  w0[1] = cvtpk(s0[2], s0[3]);
  w0[2] = cvtpk(s1[0], s1[1]);
  w0[3] = cvtpk(s1[2], s1[3]);
  w1[0] = cvtpk(s2[0], s2[1]);
  w1[1] = cvtpk(s2[2], s2[3]);
  w1[2] = cvtpk(s3[0], s3[1]);
  w1[3] = cvtpk(s3[2], s3[3]);
  pf0 = __builtin_bit_cast(short8, w0);
  pf1 = __builtin_bit_cast(short8, w1);
}

__global__ __launch_bounds__(256, 4) void attn(const short* __restrict__ Qb,
                                               const short* __restrict__ Kb,
                                               const short* __restrict__ Vtb,
                                               short* __restrict__ X) {
  // [buf][K=0/V=1][4 chunks x 64 lanes x 8 shorts]
  __shared__ short KV[2][2][2048];
  const int tid = threadIdx.x;
  const int lane = tid & 63;
  const int w = tid >> 6;
  const int l15 = lane & 15, g = lane >> 4;
  const int id = blockIdx.x;       // id = qblk*64 + bh  ->  id%8 == bh%8
  const int bh = id & 63;
  const int qblk = id >> 6;        // 0..15
  const int bb = bh >> 4, hh = bh & 15;
  const int q0 = qblk * 128 + w * 32;

  const short* Qp = Qb + ((size_t)bh * 2048 + q0) * 32;
  const short* Kp = Kb + (size_t)bh * 2048 * 32;
  const short* Vp = Vtb + (size_t)bh * 32 * 2048;

  short8 qfA = *(const short8*)(Qp + l15 * 32 + g * 8);
  short8 qfB = *(const short8*)(Qp + (16 + l15) * 32 + g * 8);

  const int kbase = 8 * (l15 >> 2) + (l15 & 3);
  const int koff = (w & 1) * 4 + (w >> 1) * 32;   // chunk w: {0,4,32,36}
  const int vrow = (w >> 1) * 16;
  const int vcol = (w & 1) * 32;
  const short* Ksrc0 = Kp + (size_t)(kbase + koff) * 32 + g * 8;
  const short* Vsrc0 = Vp + (size_t)(l15 + vrow) * 2048 + vcol + g * 8;

  f32x4 zf = {0.f, 0.f, 0.f, 0.f};
  f32x4 o_loA = zf, o_hiA = zf, o_loB = zf, o_hiB = zf;
  f32x4 accLA = zf, accLB = zf;
  u32x4 ones_u = {0x3F803F80u, 0x3F803F80u, 0x3F803F80u, 0x3F803F80u};
  const short8 ones = __builtin_bit_cast(short8, ones_u);

#define STAGE(b, t0)                                                        \
  {                                                                         \
    __builtin_amdgcn_global_load_lds((gu32*)(Ksrc0 + (size_t)(t0) * 32),    \
                                     (lu32*)&KV[b][0][w * 512], 16, 0, 0);  \
    __builtin_amdgcn_global_load_lds((gu32*)(Vsrc0 + (t0)),                 \
                                     (lu32*)&KV[b][1][w * 512], 16, 0, 0);  \
  }

#define BODY(b)                                                       \
  {                                                                   \
    short8 k0 = *(const short8*)(&KV[b][0][0 * 512 + lane * 8]);      \
    short8 k1 = *(const short8*)(&KV[b][0][1 * 512 + lane * 8]);      \
    short8 k2 = *(const short8*)(&KV[b][0][2 * 512 + lane * 8]);      \
    short8 k3 = *(const short8*)(&KV[b][0][3 * 512 + lane * 8]);      \
    short8 vlo0 = *(const short8*)(&KV[b][1][0 * 512 + lane * 8]);    \
    short8 vlo1 = *(const short8*)(&KV[b][1][1 * 512 + lane * 8]);    \
    short8 vhi0 = *(const short8*)(&KV[b][1][2 * 512 + lane * 8]);    \
    short8 vhi1 = *(const short8*)(&KV[b][1][3 * 512 + lane * 8]);    \
    short8 pfA0, pfA1, pfB0, pfB1;                                    \
    qk_half(k0, k1, k2, k3, qfA, zf, pfA0, pfA1);                     \
    qk_half(k0, k1, k2, k3, qfB, zf, pfB0, pfB1);                     \
    __builtin_amdgcn_s_setprio(1);                                    \
    accLA = MFMA16(pfA0, ones, accLA);                                \
    accLA = MFMA16(pfA1, ones, accLA);                                \
    accLB = MFMA16(pfB0, ones, accLB);                                \
    accLB = MFMA16(pfB1, ones, accLB);                                \
    o_loA = MFMA16(pfA0, vlo0, o_loA);                                \
    o_loA = MFMA16(pfA1, vlo1, o_loA);                                \
    o_hiA = MFMA16(pfA0, vhi0, o_hiA);                                \
    o_hiA = MFMA16(pfA1, vhi1, o_hiA);                                \
    o_loB = MFMA16(pfB0, vlo0, o_loB);                                \
    o_loB = MFMA16(pfB1, vlo1, o_loB);                                \
    o_hiB = MFMA16(pfB0, vhi0, o_hiB);                                \
    o_hiB = MFMA16(pfB1, vhi1, o_hiB);                                \
    __builtin_amdgcn_s_setprio(0);                                    \
  }

  STAGE(0, 0);
  __syncthreads();
  for (int t0 = 0; t0 < 2048; t0 += 128) {
    STAGE(1, t0 + 64);
    BODY(0);
    __syncthreads();
    if (t0 + 128 < 2048) {
      STAGE(0, t0 + 128);
    }
    BODY(1);
    __syncthreads();
  }
#undef STAGE
#undef BODY

#pragma unroll
  for (int i = 0; i < 4; ++i) {
    float invA = 1.0f / accLA[i];
    float invB = 1.0f / accLB[i];
    int ssA = q0 + 4 * g + i;
    size_t baseA = ((size_t)bb * 2048 + ssA) * 512 + hh * 32;
    X[baseA + l15] = f2b(o_loA[i] * invA);
    X[baseA + 16 + l15] = f2b(o_hiA[i] * invA);
    size_t baseB = baseA + (size_t)16 * 512;
    X[baseB + l15] = f2b(o_loB[i] * invB);
    X[baseB + 16 + l15] = f2b(o_hiB[i] * invB);
  }
}

// ===================== launcher =====================
extern "C" void kernel_launch(void* const* d_in, const int* in_sizes, int n_in,
                              void* d_out, int out_size, void* d_ws, size_t ws_size,
                              hipStream_t stream) {
  const float* q = (const float*)d_in[0];
  const float* k = (const float*)d_in[1];
  const float* v = (const float*)d_in[2];
  const float* Wq = (const float*)d_in[3];
  const float* Wk = (const float*)d_in[4];
  const float* Wv = (const float*)d_in[5];
  const float* Wo = (const float*)d_in[6];

  char* ws = (char*)d_ws;
  const size_t MB = 1u << 20;
  short* WqT = (short*)(ws + 0 * MB);   // [512][1024] bf16
  short* WkT = (short*)(ws + 1 * MB);
  short* WvT = (short*)(ws + 2 * MB);
  short* WoT = (short*)(ws + 3 * MB);   // [1024][512] bf16
  short* Qb  = (short*)(ws + 4 * MB);   // [64][2048][32] bf16 (8 MiB)
  short* Kb  = (short*)(ws + 12 * MB);  // [64][2048][32]
  short* Vtb = (short*)(ws + 20 * MB);  // [64][32][2048]
  short* Xb  = (short*)(ws + 28 * MB);  // [8192][512]

  prep_weights<<<8192, 256, 0, stream>>>(Wq, Wk, Wv, Wo, WqT, WkT, WvT, WoT);
  proj_gemm<<<768, 256, 0, stream>>>(q, k, v, WqT, WkT, WvT, Qb, Kb, Vtb);
  attn<<<1024, 256, 0, stream>>>(Qb, Kb, Vtb, Xb);
  out_gemm<<<512, 256, 0, stream>>>(Xb, WoT, (float*)d_out);
}

// Round 12
// 122.598 us; speedup vs baseline: 1.0039x; 1.0039x over previous
//
#include <hip/hip_runtime.h>
#include <hip/hip_bf16.h>

typedef __attribute__((ext_vector_type(8))) short short8;
typedef __attribute__((ext_vector_type(4))) float f32x4;
typedef __attribute__((ext_vector_type(4))) float fv4;
typedef __attribute__((ext_vector_type(4))) unsigned int u32x4;

#define MFMA16(a, b, c) __builtin_amdgcn_mfma_f32_16x16x32_bf16((a), (b), (c), 0, 0, 0)
#define SBAR() __builtin_amdgcn_sched_barrier(0)

typedef const __attribute__((address_space(1))) unsigned int gu32;
typedef __attribute__((address_space(3))) unsigned int lu32;

// float -> bf16 RNE (inputs are finite; no NaN handling needed)
__device__ __forceinline__ short f2b(float f) {
  unsigned int x = __builtin_bit_cast(unsigned int, f);
  x += 0x7fffu + ((x >> 16) & 1u);
  return (short)(x >> 16);
}

// packed f32x2 -> bf16x2 (RNE) in one instruction; D.lo = S0, D.hi = S1
__device__ __forceinline__ unsigned int cvtpk(float lo, float hi) {
  unsigned int r;
  asm("v_cvt_pk_bf16_f32 %0, %1, %2" : "=v"(r) : "v"(lo), "v"(hi));
  return r;
}

// hardware 2^x as a compiler-known instruction (TRANS hazards handled)
#define hexp2(x) __builtin_amdgcn_exp2f(x)

// ===================== weight prep =====================
// WqT/WkT/WvT: [512][1024] bf16, WT[n][d] = W[n>>5][d][n&31]  (B^T layout)
// Wq additionally scaled by d_model^-0.5 * log2(e) so QK^T logits are base-2.
// WoT: [1024][512] bf16, WoT[n][k] = Wo[k][n]
__global__ void prep_weights(const float* __restrict__ Wq, const float* __restrict__ Wk,
                             const float* __restrict__ Wv, const float* __restrict__ Wo,
                             short* __restrict__ WqT, short* __restrict__ WkT,
                             short* __restrict__ WvT, short* __restrict__ WoT) {
  const float SC2 = 0.045084220027780106f;  // (1/32) * log2(e)
  int idx = blockIdx.x * 256 + threadIdx.x;
  if (idx < 3 * 512 * 1024) {
    int wsel = idx >> 19;
    int rem = idx & ((1 << 19) - 1);
    int n = rem >> 10;
    int d = rem & 1023;
    const float* W = (wsel == 0) ? Wq : ((wsel == 1) ? Wk : Wv);
    short* WT = (wsel == 0) ? WqT : ((wsel == 1) ? WkT : WvT);
    float v = W[(n >> 5) * (1024 * 32) + d * 32 + (n & 31)];
    if (wsel == 0) v *= SC2;
    WT[n * 1024 + d] = f2b(v);
  } else {
    int idx2 = idx - 3 * 512 * 1024;
    int n = idx2 >> 9;
    int kk = idx2 & 511;
    WoT[n * 512 + kk] = f2b(Wo[kk * 1024 + n]);
  }
}

// ===================== projection GEMM (BK=32, double-buffered) =====================
// C = A[M,1024] * BT[512,1024]^T per z. 128x128 tile, 4 waves (2x2), BK=32.
// A: global f32 -> regs -> cvtpk -> bf16 ds_write (halves LDS bytes vs f32
// tile; conversion done once at staging). B: global_load_lds with
// pre-swizzled source. Both tiles [128][32] bf16, 16B slots XOR-swizzled by
// (row>>1)&3 on write AND read (involution). Double-buffered: loads for
// step k+1 issue BEFORE compute(k) (SBAR-walled vs compiler sinking),
// A ds_write lands after compute, one barrier per step -> L2 latency hidden.
// Grid 768 = 256 CU x 3 (zero tail); id%8==bm%8 pins A panels per XCD.
__global__ __launch_bounds__(256, 3) void proj_gemm(
    const float* __restrict__ q, const float* __restrict__ k, const float* __restrict__ v,
    const short* __restrict__ WqT, const short* __restrict__ WkT, const short* __restrict__ WvT,
    short* __restrict__ Qb, short* __restrict__ Kb, short* __restrict__ Vtb) {
  __shared__ char smem[32768];  // A bufs @0,@8192 ; B bufs @16384,@24576
  const int tid = threadIdx.x;
  const int lane = tid & 63;
  const int w = tid >> 6;
  const int l15 = lane & 15, g = lane >> 4;
  const int wm = (w >> 1) * 64, wn = (w & 1) * 64;
  const int id = blockIdx.x;
  const int bm = id & 63;
  const int r = id >> 6;
  const int bn = r & 3;
  const int z = r >> 2;
  const float* A = (z == 0) ? q : ((z == 1) ? k : v);
  const short* BT = (z == 0) ? WqT : ((z == 1) ? WkT : WvT);
  const int bm0 = bm * 128, bn0 = bn * 128;

  // A staging: lane owns row w*32+(lane>>1), 16 f32 half (lane&1)
  const int arow = w * 32 + (lane >> 1);
  const int ahalf = lane & 1;
  const int aswz = (arow >> 1) & 3;
  const float* Ag = A + (size_t)(bm0 + arow) * 1024 + ahalf * 16;
  const int aw_off0 = arow * 64 + (((2 * ahalf) ^ aswz) * 16);
  const int aw_off1 = arow * 64 + (((2 * ahalf + 1) ^ aswz) * 16);

  // B staging: 2 gl_lds/wave, 16 rows each, pre-swizzled global source
  const int brow0 = w * 32 + (lane >> 2);
  const int brow1 = brow0 + 16;
  const short* Bg0 = BT + (size_t)(bn0 + brow0) * 1024 + 8 * ((lane & 3) ^ ((brow0 >> 1) & 3));
  const short* Bg1 = BT + (size_t)(bn0 + brow1) * 1024 + 8 * ((lane & 3) ^ ((brow1 >> 1) & 3));

  f32x4 zf = {0.f, 0.f, 0.f, 0.f};
  f32x4 acc[4][4];
#pragma unroll
  for (int a = 0; a < 4; ++a)
#pragma unroll
    for (int bq = 0; bq < 4; ++bq) acc[a][bq] = zf;

  fv4 fa0, fa1, fa2, fa3;
#define GLOADA(k0)                          \
  fa0 = *(const fv4*)(Ag + (k0));           \
  fa1 = *(const fv4*)(Ag + (k0) + 4);       \
  fa2 = *(const fv4*)(Ag + (k0) + 8);       \
  fa3 = *(const fv4*)(Ag + (k0) + 12);

#define WRITEA(aoff)                                                  \
  {                                                                   \
    u32x4 wv0, wv1;                                                   \
    wv0[0] = cvtpk(fa0[0], fa0[1]);                                   \
    wv0[1] = cvtpk(fa0[2], fa0[3]);                                   \
    wv0[2] = cvtpk(fa1[0], fa1[1]);                                   \
    wv0[3] = cvtpk(fa1[2], fa1[3]);                                   \
    wv1[0] = cvtpk(fa2[0], fa2[1]);                                   \
    wv1[1] = cvtpk(fa2[2], fa2[3]);                                   \
    wv1[2] = cvtpk(fa3[0], fa3[1]);                                   \
    wv1[3] = cvtpk(fa3[2], fa3[3]);                                   \
    *(short8*)(smem + (aoff) + aw_off0) = __builtin_bit_cast(short8, wv0); \
    *(short8*)(smem + (aoff) + aw_off1) = __builtin_bit_cast(short8, wv1); \
  }

#define STAGEB(boff, k0)                                                      \
  {                                                                           \
    __builtin_amdgcn_global_load_lds((gu32*)(Bg0 + (k0)),                     \
                                     (lu32*)(smem + (boff) + w * 2048), 16, 0, 0); \
    __builtin_amdgcn_global_load_lds((gu32*)(Bg1 + (k0)),                     \
                                     (lu32*)(smem + (boff) + w * 2048 + 1024), 16, 0, 0); \
  }

#define COMPUTE(aoff, boff)                                                    \
  {                                                                            \
    short8 af[4], bfr[4];                                                      \
    _Pragma("unroll") for (int mf = 0; mf < 4; ++mf) {                         \
      int ar = wm + mf * 16 + l15;                                             \
      af[mf] = *(const short8*)(smem + (aoff) + ar * 64 +                      \
                                ((g ^ ((ar >> 1) & 3)) * 16));                 \
    }                                                                          \
    _Pragma("unroll") for (int nf = 0; nf < 4; ++nf) {                         \
      int br = wn + nf * 16 + l15;                                             \
      bfr[nf] = *(const short8*)(smem + (boff) + br * 64 +                     \
                                 ((g ^ ((br >> 1) & 3)) * 16));                \
    }                                                                          \
    _Pragma("unroll") for (int mf = 0; mf < 4; ++mf)                           \
        _Pragma("unroll") for (int nf = 0; nf < 4; ++nf)                       \
            acc[mf][nf] = MFMA16(af[mf], bfr[nf], acc[mf][nf]);                \
  }

  // prologue: fill buffer 0
  GLOADA(0);
  STAGEB(16384, 0);
  WRITEA(0);
  __syncthreads();

  for (int k0 = 0; k0 < 1024; k0 += 32) {
    const int cur = (k0 >> 5) & 1;
    const int nxt = cur ^ 1;
    const int acur = cur * 8192, anxt = nxt * 8192;
    const int bcur = 16384 + cur * 8192, bnxt = 16384 + nxt * 8192;
    if (k0 + 32 < 1024) {
      GLOADA(k0 + 32);
      STAGEB(bnxt, k0 + 32);
    }
    SBAR();  // pin loads above the compute
    COMPUTE(acur, bcur);
    SBAR();
    if (k0 + 32 < 1024) WRITEA(anxt);
    __syncthreads();  // drains lgkm (A write) + vm (B gl_lds) for next step
  }
#undef GLOADA
#undef WRITEA
#undef STAGEB
#undef COMPUTE

#pragma unroll
  for (int mf = 0; mf < 4; ++mf)
#pragma unroll
    for (int nf = 0; nf < 4; ++nf)
#pragma unroll
      for (int i = 0; i < 4; ++i) {
        int row = bm0 + wm + mf * 16 + g * 4 + i;  // m index (b*2048+s)
        int col = bn0 + wn + nf * 16 + l15;        // n index (h*32+e)
        int bb = row >> 11, ss = row & 2047;
        int hh = col >> 5, ee = col & 31;
        short val = f2b(acc[mf][nf][i]);
        if (z == 2)
          Vtb[((size_t)(bb * 16 + hh) * 32 + ee) * 2048 + ss] = val;
        else if (z == 1)
          Kb[((size_t)(bb * 16 + hh) * 2048 + ss) * 32 + ee] = val;
        else
          Qb[((size_t)(bb * 16 + hh) * 2048 + ss) * 32 + ee] = val;
      }
}

// ===================== output GEMM (BK=32, double-buffered) =====================
// C[8192,1024] = X[8192,512] * WoT[1024,512]^T. Both bf16 via gl_lds with
// pre-swizzled sources; same dbuf pipeline. Grid 512 = 256 CU x 2, no tail.
__global__ __launch_bounds__(256, 2) void out_gemm(const short* __restrict__ X,
                                                   const short* __restrict__ WoT,
                                                   float* __restrict__ out) {
  __shared__ char smem[32768];  // A bufs @0,@8192 ; B bufs @16384,@24576
  const int tid = threadIdx.x;
  const int lane = tid & 63;
  const int w = tid >> 6;
  const int l15 = lane & 15, g = lane >> 4;
  const int wm = (w >> 1) * 64, wn = (w & 1) * 64;
  const int id = blockIdx.x;
  const int bm0 = (id & 63) * 128, bn0 = (id >> 6) * 128;

  const int row0 = w * 32 + (lane >> 2);
  const int row1 = row0 + 16;
  const int sl = lane & 3;
  const short* Ag0 = X + (size_t)(bm0 + row0) * 512 + 8 * (sl ^ ((row0 >> 1) & 3));
  const short* Ag1 = X + (size_t)(bm0 + row1) * 512 + 8 * (sl ^ ((row1 >> 1) & 3));
  const short* Bg0 = WoT + (size_t)(bn0 + row0) * 512 + 8 * (sl ^ ((row0 >> 1) & 3));
  const short* Bg1 = WoT + (size_t)(bn0 + row1) * 512 + 8 * (sl ^ ((row1 >> 1) & 3));

  f32x4 zf = {0.f, 0.f, 0.f, 0.f};
  f32x4 acc[4][4];
#pragma unroll
  for (int a = 0; a < 4; ++a)
#pragma unroll
    for (int bq = 0; bq < 4; ++bq) acc[a][bq] = zf;

#define STAGE(aoff, boff, k0)                                                     \
  {                                                                               \
    __builtin_amdgcn_global_load_lds((gu32*)(Ag0 + (k0)),                         \
                                     (lu32*)(smem + (aoff) + w * 2048), 16, 0, 0); \
    __builtin_amdgcn_global_load_lds((gu32*)(Ag1 + (k0)),                         \
                                     (lu32*)(smem + (aoff) + w * 2048 + 1024), 16, 0, 0); \
    __builtin_amdgcn_global_load_lds((gu32*)(Bg0 + (k0)),                         \
                                     (lu32*)(smem + (boff) + w * 2048), 16, 0, 0); \
    __builtin_amdgcn_global_load_lds((gu32*)(Bg1 + (k0)),                         \
                                     (lu32*)(smem + (boff) + w * 2048 + 1024), 16, 0, 0); \
  }

#define COMPUTE(aoff, boff)                                                    \
  {                                                                            \
    short8 af[4], bfr[4];                                                      \
    _Pragma("unroll") for (int mf = 0; mf < 4; ++mf) {                         \
      int ar = wm + mf * 16 + l15;                                             \
      af[mf] = *(const short8*)(smem + (aoff) + ar * 64 +                      \
                                ((g ^ ((ar >> 1) & 3)) * 16));                 \
    }                                                                          \
    _Pragma("unroll") for (int nf = 0; nf < 4; ++nf) {                         \
      int br = wn + nf * 16 + l15;                                             \
      bfr[nf] = *(const short8*)(smem + (boff) + br * 64 +                     \
                                 ((g ^ ((br >> 1) & 3)) * 16));                \
    }                                                                          \
    _Pragma("unroll") for (int mf = 0; mf < 4; ++mf)                           \
        _Pragma("unroll") for (int nf = 0; nf < 4; ++nf)                       \
            acc[mf][nf] = MFMA16(af[mf], bfr[nf], acc[mf][nf]);                \
  }

  STAGE(0, 16384, 0);
  __syncthreads();
  for (int k0 = 0; k0 < 512; k0 += 32) {
    const int cur = (k0 >> 5) & 1;
    const int nxt = cur ^ 1;
    if (k0 + 32 < 512) {
      STAGE(nxt * 8192, 16384 + nxt * 8192, k0 + 32);
    }
    SBAR();
    COMPUTE(cur * 8192, 16384 + cur * 8192);
    SBAR();
    __syncthreads();
  }
#undef STAGE
#undef COMPUTE

#pragma unroll
  for (int mf = 0; mf < 4; ++mf)
#pragma unroll
    for (int nf = 0; nf < 4; ++nf)
#pragma unroll
      for (int i = 0; i < 4; ++i) {
        int row = bm0 + wm + mf * 16 + g * 4 + i;
        int col = bn0 + wn + nf * 16 + l15;
        out[(size_t)row * 1024 + col] = acc[mf][nf][i];
      }
}

// ===================== fused flash attention =====================
// (unchanged from R9 — LDS-staged K/V via gl_lds, swapped QK^T, permuted
// K rows, no online max, ones-MFMA denominator, head-pinned XCD grid)
__device__ __forceinline__ void qk_half(short8 k0, short8 k1, short8 k2, short8 k3,
                                        short8 qf, const f32x4& zf,
                                        short8& pf0, short8& pf1) {
  f32x4 s0 = MFMA16(k0, qf, zf);
  f32x4 s1 = MFMA16(k1, qf, zf);
  f32x4 s2 = MFMA16(k2, qf, zf);
  f32x4 s3 = MFMA16(k3, qf, zf);
#pragma unroll
  for (int i = 0; i < 4; ++i) {
    s0[i] = hexp2(s0[i]);
    s1[i] = hexp2(s1[i]);
    s2[i] = hexp2(s2[i]);
    s3[i] = hexp2(s3[i]);
  }
  u32x4 w0, w1;
  w0[0] = cvtpk(s0[0], s0[1]);
  w0[1] = cvtpk(s0[2], s0[3]);
  w0[2] = cvtpk(s1[0], s1[1]);
  w0[3] = cvtpk(s1[2], s1[3]);
  w1[0] = cvtpk(s2[0], s2[1]);
  w1[1] = cvtpk(s2[2], s2[3]);
  w1[2] = cvtpk(s3[0], s3[1]);
  w1[3] = cvtpk(s3[2], s3[3]);
  pf0 = __builtin_bit_cast(short8, w0);
  pf1 = __builtin_bit_cast(short8, w1);
}

__global__ __launch_bounds__(256, 4) void attn(const short* __restrict__ Qb,
                                               const short* __restrict__ Kb,
                                               const short* __restrict__ Vtb,
                                               short* __restrict__ X) {
  // [buf][K=0/V=1][4 chunks x 64 lanes x 8 shorts]
  __shared__ short KV[2][2][2048];
  const int tid = threadIdx.x;
  const int lane = tid & 63;
  const int w = tid >> 6;
  const int l15 = lane & 15, g = lane >> 4;
  const int id = blockIdx.x;       // id = qblk*64 + bh  ->  id%8 == bh%8
  const int bh = id & 63;
  const int qblk = id >> 6;        // 0..15
  const int bb = bh >> 4, hh = bh & 15;
  const int q0 = qblk * 128 + w * 32;

  const short* Qp = Qb + ((size_t)bh * 2048 + q0) * 32;
  const short* Kp = Kb + (size_t)bh * 2048 * 32;
  const short* Vp = Vtb + (size_t)bh * 32 * 2048;

  short8 qfA = *(const short8*)(Qp + l15 * 32 + g * 8);
  short8 qfB = *(const short8*)(Qp + (16 + l15) * 32 + g * 8);

  const int kbase = 8 * (l15 >> 2) + (l15 & 3);
  const int koff = (w & 1) * 4 + (w >> 1) * 32;   // chunk w: {0,4,32,36}
  const int vrow = (w >> 1) * 16;
  const int vcol = (w & 1) * 32;
  const short* Ksrc0 = Kp + (size_t)(kbase + koff) * 32 + g * 8;
  const short* Vsrc0 = Vp + (size_t)(l15 + vrow) * 2048 + vcol + g * 8;

  f32x4 zf = {0.f, 0.f, 0.f, 0.f};
  f32x4 o_loA = zf, o_hiA = zf, o_loB = zf, o_hiB = zf;
  f32x4 accLA = zf, accLB = zf;
  u32x4 ones_u = {0x3F803F80u, 0x3F803F80u, 0x3F803F80u, 0x3F803F80u};
  const short8 ones = __builtin_bit_cast(short8, ones_u);

#define STAGE(b, t0)                                                        \
  {                                                                         \
    __builtin_amdgcn_global_load_lds((gu32*)(Ksrc0 + (size_t)(t0) * 32),    \
                                     (lu32*)&KV[b][0][w * 512], 16, 0, 0);  \
    __builtin_amdgcn_global_load_lds((gu32*)(Vsrc0 + (t0)),                 \
                                     (lu32*)&KV[b][1][w * 512], 16, 0, 0);  \
  }

#define BODY(b)                                                       \
  {                                                                   \
    short8 k0 = *(const short8*)(&KV[b][0][0 * 512 + lane * 8]);      \
    short8 k1 = *(const short8*)(&KV[b][0][1 * 512 + lane * 8]);      \
    short8 k2 = *(const short8*)(&KV[b][0][2 * 512 + lane * 8]);      \
    short8 k3 = *(const short8*)(&KV[b][0][3 * 512 + lane * 8]);      \
    short8 vlo0 = *(const short8*)(&KV[b][1][0 * 512 + lane * 8]);    \
    short8 vlo1 = *(const short8*)(&KV[b][1][1 * 512 + lane * 8]);    \
    short8 vhi0 = *(const short8*)(&KV[b][1][2 * 512 + lane * 8]);    \
    short8 vhi1 = *(const short8*)(&KV[b][1][3 * 512 + lane * 8]);    \
    short8 pfA0, pfA1, pfB0, pfB1;                                    \
    qk_half(k0, k1, k2, k3, qfA, zf, pfA0, pfA1);                     \
    qk_half(k0, k1, k2, k3, qfB, zf, pfB0, pfB1);                     \
    __builtin_amdgcn_s_setprio(1);                                    \
    accLA = MFMA16(pfA0, ones, accLA);                                \
    accLA = MFMA16(pfA1, ones, accLA);                                \
    accLB = MFMA16(pfB0, ones, accLB);                                \
    accLB = MFMA16(pfB1, ones, accLB);                                \
    o_loA = MFMA16(pfA0, vlo0, o_loA);                                \
    o_loA = MFMA16(pfA1, vlo1, o_loA);                                \
    o_hiA = MFMA16(pfA0, vhi0, o_hiA);                                \
    o_hiA = MFMA16(pfA1, vhi1, o_hiA);                                \
    o_loB = MFMA16(pfB0, vlo0, o_loB);                                \
    o_loB = MFMA16(pfB1, vlo1, o_loB);                                \
    o_hiB = MFMA16(pfB0, vhi0, o_hiB);                                \
    o_hiB = MFMA16(pfB1, vhi1, o_hiB);                                \
    __builtin_amdgcn_s_setprio(0);                                    \
  }

  STAGE(0, 0);
  __syncthreads();
  for (int t0 = 0; t0 < 2048; t0 += 128) {
    STAGE(1, t0 + 64);
    BODY(0);
    __syncthreads();
    if (t0 + 128 < 2048) {
      STAGE(0, t0 + 128);
    }
    BODY(1);
    __syncthreads();
  }
#undef STAGE
#undef BODY

#pragma unroll
  for (int i = 0; i < 4; ++i) {
    float invA = 1.0f / accLA[i];
    float invB = 1.0f / accLB[i];
    int ssA = q0 + 4 * g + i;
    size_t baseA = ((size_t)bb * 2048 + ssA) * 512 + hh * 32;
    X[baseA + l15] = f2b(o_loA[i] * invA);
    X[baseA + 16 + l15] = f2b(o_hiA[i] * invA);
    size_t baseB = baseA + (size_t)16 * 512;
    X[baseB + l15] = f2b(o_loB[i] * invB);
    X[baseB + 16 + l15] = f2b(o_hiB[i] * invB);
  }
}

// ===================== launcher =====================
extern "C" void kernel_launch(void* const* d_in, const int* in_sizes, int n_in,
                              void* d_out, int out_size, void* d_ws, size_t ws_size,
                              hipStream_t stream) {
  const float* q = (const float*)d_in[0];
  const float* k = (const float*)d_in[1];
  const float* v = (const float*)d_in[2];
  const float* Wq = (const float*)d_in[3];
  const float* Wk = (const float*)d_in[4];
  const float* Wv = (const float*)d_in[5];
  const float* Wo = (const float*)d_in[6];

  char* ws = (char*)d_ws;
  const size_t MB = 1u << 20;
  short* WqT = (short*)(ws + 0 * MB);   // [512][1024] bf16
  short* WkT = (short*)(ws + 1 * MB);
  short* WvT = (short*)(ws + 2 * MB);
  short* WoT = (short*)(ws + 3 * MB);   // [1024][512] bf16
  short* Qb  = (short*)(ws + 4 * MB);   // [64][2048][32] bf16 (8 MiB)
  short* Kb  = (short*)(ws + 12 * MB);  // [64][2048][32]
  short* Vtb = (short*)(ws + 20 * MB);  // [64][32][2048]
  short* Xb  = (short*)(ws + 28 * MB);  // [8192][512]

  prep_weights<<<8192, 256, 0, stream>>>(Wq, Wk, Wv, Wo, WqT, WkT, WvT, WoT);
  proj_gemm<<<768, 256, 0, stream>>>(q, k, v, WqT, WkT, WvT, Qb, Kb, Vtb);
  attn<<<1024, 256, 0, stream>>>(Qb, Kb, Vtb, Xb);
  out_gemm<<<512, 256, 0, stream>>>(Xb, WoT, (float*)d_out);
}

// Round 13
// 118.147 us; speedup vs baseline: 1.0417x; 1.0377x over previous
//
#include <hip/hip_runtime.h>
#include <hip/hip_bf16.h>

typedef __attribute__((ext_vector_type(8))) short short8;
typedef __attribute__((ext_vector_type(4))) float f32x4;
typedef __attribute__((ext_vector_type(4))) float fv4;
typedef __attribute__((ext_vector_type(4))) unsigned int u32x4;

#define MFMA16(a, b, c) __builtin_amdgcn_mfma_f32_16x16x32_bf16((a), (b), (c), 0, 0, 0)
#define SBAR() __builtin_amdgcn_sched_barrier(0)
#define RBAR() __builtin_amdgcn_s_barrier()

typedef const __attribute__((address_space(1))) unsigned int gu32;
typedef __attribute__((address_space(3))) unsigned int lu32;

// float -> bf16 RNE (inputs are finite; no NaN handling needed)
__device__ __forceinline__ short f2b(float f) {
  unsigned int x = __builtin_bit_cast(unsigned int, f);
  x += 0x7fffu + ((x >> 16) & 1u);
  return (short)(x >> 16);
}

// packed f32x2 -> bf16x2 (RNE) in one instruction; D.lo = S0, D.hi = S1
__device__ __forceinline__ unsigned int cvtpk(float lo, float hi) {
  unsigned int r;
  asm("v_cvt_pk_bf16_f32 %0, %1, %2" : "=v"(r) : "v"(lo), "v"(hi));
  return r;
}

// hardware 2^x as a compiler-known instruction (TRANS hazards handled)
#define hexp2(x) __builtin_amdgcn_exp2f(x)

// ===================== weight prep =====================
// BTall = [WqT|WkT|WvT] contiguous: [1536][1024] bf16, n-major; Wq scaled by
// d_model^-0.5 * log2(e). WoT: [1024][512] bf16.
__global__ void prep_weights(const float* __restrict__ Wq, const float* __restrict__ Wk,
                             const float* __restrict__ Wv, const float* __restrict__ Wo,
                             short* __restrict__ WqT, short* __restrict__ WkT,
                             short* __restrict__ WvT, short* __restrict__ WoT) {
  const float SC2 = 0.045084220027780106f;  // (1/32) * log2(e)
  int idx = blockIdx.x * 256 + threadIdx.x;
  if (idx < 3 * 512 * 1024) {
    int wsel = idx >> 19;
    int rem = idx & ((1 << 19) - 1);
    int n = rem >> 10;
    int d = rem & 1023;
    const float* W = (wsel == 0) ? Wq : ((wsel == 1) ? Wk : Wv);
    short* WT = (wsel == 0) ? WqT : ((wsel == 1) ? WkT : WvT);
    float v = W[(n >> 5) * (1024 * 32) + d * 32 + (n & 31)];
    if (wsel == 0) v *= SC2;
    WT[n * 1024 + d] = f2b(v);
  } else {
    int idx2 = idx - 3 * 512 * 1024;
    int n = idx2 >> 9;
    int kk = idx2 & 511;
    WoT[n * 512 + kk] = f2b(Wo[kk * 1024 + n]);
  }
}

// ===================== fused projection GEMM =====================
// C[8192,1536] = A_f32[8192,1024] * BTall[1536,1024]^T, one GEMM for Q,K,V
// (weights contiguous). 128x128 tile, BK=32, 4 waves (2x2).
// T4 pipeline (m218: counted vmcnt vs drain-0 = +38..73%): per step
//   stage(next buf): 6x global_load_lds (A f32 16KB, B bf16 8KB)
//   s_waitcnt vmcnt(6)   <- waits CURRENT buf only; prefetch stays in flight
//   raw s_barrier / compute / raw s_barrier   (never vmcnt(0) in loop)
// A staged as f32 (gl_lds, no reg roundtrip to sink), cvtpk at frag read.
// Swizzles (verified conflict-free R12): A slots u^=(row&7), B u^=((row>>1)&3),
// applied to pre-swizzled global source AND read address (involution).
// LDS 48KB dbuf -> 3 blocks/CU; grid 768 = 256x3 exact; id%8==bm%8 XCD-pins.
__global__ __launch_bounds__(256, 3) void proj_gemm(
    const float* __restrict__ q, const float* __restrict__ k, const float* __restrict__ v,
    const short* __restrict__ BTall,
    short* __restrict__ Qb, short* __restrict__ Kb, short* __restrict__ Vtb) {
  __shared__ char smem[49152];  // buf0: A@0(16K) B@16384(8K); buf1: A@24576 B@40960
  const int tid = threadIdx.x;
  const int lane = tid & 63;
  const int w = tid >> 6;
  const int l15 = lane & 15, g = lane >> 4;
  const int wm = (w >> 1) * 64, wn = (w & 1) * 64;
  const int id = blockIdx.x;
  const int bm = id & 63;
  const int bn = id >> 6;  // 0..11
  const int bm0 = bm * 128, bn0 = bn * 128;
  const int z = blockIdx.y;  // unused (1)
  (void)z;
  const float* A = q;  // q,k,v are contiguous? NO — separate ptrs; A chosen per n at store? Not needed: A is always the same input? WRONG.
  // NOTE: Q/K/V use DIFFERENT A inputs (q,k,v). The fused-N trick applies to
  // the weights only if A differs per 512-col group — it does NOT. So fuse
  // differently: z = bn/4 selects input, bn%4 selects the 512-wide group.
  (void)A;

  const int zz = bn >> 2;          // 0:q 1:k 2:v
  const int bnz = bn & 3;          // n-block within this input's 512 cols
  const float* Az = (zz == 0) ? q : ((zz == 1) ? k : v);
  const short* BT = BTall + (size_t)zz * 512 * 1024;
  const int bn0z = bnz * 128;

  // A staging: 4 instr/wave, rows 32w+8i+(lane>>3), slot u=lane&7 (16B of 8)
  const int ar = (lane >> 3);
  const int au = lane & 7;
  // B staging: 2 instr/wave, rows 32w+16i+(lane>>2), slot u=lane&3 (16B of 4)
  const int br = (lane >> 2);
  const int bu = lane & 3;

  f32x4 zf = {0.f, 0.f, 0.f, 0.f};
  f32x4 acc[4][4];
#pragma unroll
  for (int a = 0; a < 4; ++a)
#pragma unroll
    for (int bq = 0; bq < 4; ++bq) acc[a][bq] = zf;

#define STAGE(base, k0)                                                        \
  {                                                                            \
    _Pragma("unroll") for (int i = 0; i < 4; ++i) {                            \
      int row = 32 * w + 8 * i + ar;                                           \
      __builtin_amdgcn_global_load_lds(                                        \
          (gu32*)(Az + (size_t)(bm0 + row) * 1024 + (k0) + 4 * (au ^ (row & 7))), \
          (lu32*)(smem + (base) + w * 4096 + i * 1024), 16, 0, 0);             \
    }                                                                          \
    _Pragma("unroll") for (int i = 0; i < 2; ++i) {                            \
      int row = 32 * w + 16 * i + br;                                          \
      __builtin_amdgcn_global_load_lds(                                        \
          (gu32*)(BT + (size_t)(bn0z + row) * 1024 + (k0) +                    \
                  8 * (bu ^ ((row >> 1) & 3))),                                \
          (lu32*)(smem + (base) + 16384 + w * 2048 + i * 1024), 16, 0, 0);     \
    }                                                                          \
  }

#define COMPUTE(base)                                                          \
  {                                                                            \
    short8 af[4], bfr[4];                                                      \
    _Pragma("unroll") for (int mf = 0; mf < 4; ++mf) {                         \
      int row = wm + mf * 16 + l15;                                            \
      fv4 a0 = *(const fv4*)(smem + (base) + row * 128 +                       \
                             (((2 * g) ^ (row & 7)) * 16));                    \
      fv4 a1 = *(const fv4*)(smem + (base) + row * 128 +                       \
                             (((2 * g + 1) ^ (row & 7)) * 16));                \
      u32x4 wv;                                                                \
      wv[0] = cvtpk(a0[0], a0[1]);                                             \
      wv[1] = cvtpk(a0[2], a0[3]);                                             \
      wv[2] = cvtpk(a1[0], a1[1]);                                             \
      wv[3] = cvtpk(a1[2], a1[3]);                                             \
      af[mf] = __builtin_bit_cast(short8, wv);                                 \
    }                                                                          \
    _Pragma("unroll") for (int nf = 0; nf < 4; ++nf) {                         \
      int row = wn + nf * 16 + l15;                                            \
      bfr[nf] = *(const short8*)(smem + (base) + 16384 + row * 64 +            \
                                 ((g ^ ((row >> 1) & 3)) * 16));               \
    }                                                                          \
    _Pragma("unroll") for (int mf = 0; mf < 4; ++mf)                           \
        _Pragma("unroll") for (int nf = 0; nf < 4; ++nf)                       \
            acc[mf][nf] = MFMA16(af[mf], bfr[nf], acc[mf][nf]);                \
  }

  STAGE(0, 0);
  for (int k0 = 0; k0 < 1024; k0 += 32) {
    const int cur = (k0 >> 5) & 1;
    const int cbase = cur * 24576;
    const int nbase = (cur ^ 1) * 24576;
    if (k0 + 32 < 1024) {
      STAGE(nbase, k0 + 32);
      asm volatile("s_waitcnt vmcnt(6)" ::: "memory");
    } else {
      asm volatile("s_waitcnt vmcnt(0)" ::: "memory");
    }
    RBAR();  // all waves' current-buf chunks landed
    SBAR();
    COMPUTE(cbase);
    RBAR();  // all waves done reading before next stage overwrites
  }
#undef STAGE
#undef COMPUTE

#pragma unroll
  for (int mf = 0; mf < 4; ++mf)
#pragma unroll
    for (int nf = 0; nf < 4; ++nf)
#pragma unroll
      for (int i = 0; i < 4; ++i) {
        int row = bm0 + wm + mf * 16 + g * 4 + i;  // m index (b*2048+s)
        int col = bn0z + wn + nf * 16 + l15;       // n within this input's 512
        int bb = row >> 11, ss = row & 2047;
        int hh = col >> 5, ee = col & 31;
        short val = f2b(acc[mf][nf][i]);
        if (zz == 2)
          Vtb[((size_t)(bb * 16 + hh) * 32 + ee) * 2048 + ss] = val;
        else if (zz == 1)
          Kb[((size_t)(bb * 16 + hh) * 2048 + ss) * 32 + ee] = val;
        else
          Qb[((size_t)(bb * 16 + hh) * 2048 + ss) * 32 + ee] = val;
      }
}

// ===================== output GEMM (T4 pipeline) =====================
// C[8192,1024] = X[8192,512] * WoT[1024,512]^T, both bf16. BK=32, 16 steps.
// Same counted-vmcnt structure, 4 gl_lds/step -> vmcnt(4). Grid 512 = 256x2.
__global__ __launch_bounds__(256, 2) void out_gemm(const short* __restrict__ X,
                                                   const short* __restrict__ WoT,
                                                   float* __restrict__ out) {
  __shared__ char smem[32768];  // buf: A 8K + B 8K; bufs @0, @16384
  const int tid = threadIdx.x;
  const int lane = tid & 63;
  const int w = tid >> 6;
  const int l15 = lane & 15, g = lane >> 4;
  const int wm = (w >> 1) * 64, wn = (w & 1) * 64;
  const int id = blockIdx.x;
  const int bm0 = (id & 63) * 128, bn0 = (id >> 6) * 128;

  const int br = (lane >> 2);
  const int bu = lane & 3;

  f32x4 zf = {0.f, 0.f, 0.f, 0.f};
  f32x4 acc[4][4];
#pragma unroll
  for (int a = 0; a < 4; ++a)
#pragma unroll
    for (int bq = 0; bq < 4; ++bq) acc[a][bq] = zf;

#define STAGE(base, k0)                                                        \
  {                                                                            \
    _Pragma("unroll") for (int i = 0; i < 2; ++i) {                            \
      int row = 32 * w + 16 * i + br;                                          \
      __builtin_amdgcn_global_load_lds(                                        \
          (gu32*)(X + (size_t)(bm0 + row) * 512 + (k0) +                       \
                  8 * (bu ^ ((row >> 1) & 3))),                                \
          (lu32*)(smem + (base) + w * 2048 + i * 1024), 16, 0, 0);             \
      __builtin_amdgcn_global_load_lds(                                        \
          (gu32*)(WoT + (size_t)(bn0 + row) * 512 + (k0) +                     \
                  8 * (bu ^ ((row >> 1) & 3))),                                \
          (lu32*)(smem + (base) + 8192 + w * 2048 + i * 1024), 16, 0, 0);      \
    }                                                                          \
  }

#define COMPUTE(base)                                                          \
  {                                                                            \
    short8 af[4], bfr[4];                                                      \
    _Pragma("unroll") for (int mf = 0; mf < 4; ++mf) {                         \
      int row = wm + mf * 16 + l15;                                            \
      af[mf] = *(const short8*)(smem + (base) + row * 64 +                     \
                                ((g ^ ((row >> 1) & 3)) * 16));                \
    }                                                                          \
    _Pragma("unroll") for (int nf = 0; nf < 4; ++nf) {                         \
      int row = wn + nf * 16 + l15;                                            \
      bfr[nf] = *(const short8*)(smem + (base) + 8192 + row * 64 +             \
                                 ((g ^ ((row >> 1) & 3)) * 16));               \
    }                                                                          \
    _Pragma("unroll") for (int mf = 0; mf < 4; ++mf)                           \
        _Pragma("unroll") for (int nf = 0; nf < 4; ++nf)                       \
            acc[mf][nf] = MFMA16(af[mf], bfr[nf], acc[mf][nf]);                \
  }

  STAGE(0, 0);
  for (int k0 = 0; k0 < 512; k0 += 32) {
    const int cur = (k0 >> 5) & 1;
    const int cbase = cur * 16384;
    const int nbase = (cur ^ 1) * 16384;
    if (k0 + 32 < 512) {
      STAGE(nbase, k0 + 32);
      asm volatile("s_waitcnt vmcnt(4)" ::: "memory");
    } else {
      asm volatile("s_waitcnt vmcnt(0)" ::: "memory");
    }
    RBAR();
    SBAR();
    COMPUTE(cbase);
    RBAR();
  }
#undef STAGE
#undef COMPUTE

#pragma unroll
  for (int mf = 0; mf < 4; ++mf)
#pragma unroll
    for (int nf = 0; nf < 4; ++nf)
#pragma unroll
      for (int i = 0; i < 4; ++i) {
        int row = bm0 + wm + mf * 16 + g * 4 + i;
        int col = bn0 + wn + nf * 16 + l15;
        out[(size_t)row * 1024 + col] = acc[mf][nf][i];
      }
}

// ===================== fused flash attention =====================
// (unchanged from R9 — LDS-staged K/V via gl_lds, swapped QK^T, permuted
// K rows, no online max, ones-MFMA denominator, head-pinned XCD grid)
__device__ __forceinline__ void qk_half(short8 k0, short8 k1, short8 k2, short8 k3,
                                        short8 qf, const f32x4& zf,
                                        short8& pf0, short8& pf1) {
  f32x4 s0 = MFMA16(k0, qf, zf);
  f32x4 s1 = MFMA16(k1, qf, zf);
  f32x4 s2 = MFMA16(k2, qf, zf);
  f32x4 s3 = MFMA16(k3, qf, zf);
#pragma unroll
  for (int i = 0; i < 4; ++i) {
    s0[i] = hexp2(s0[i]);
    s1[i] = hexp2(s1[i]);
    s2[i] = hexp2(s2[i]);
    s3[i] = hexp2(s3[i]);
  }
  u32x4 w0, w1;
  w0[0] = cvtpk(s0[0], s0[1]);
  w0[1] = cvtpk(s0[2], s0[3]);
  w0[2] = cvtpk(s1[0], s1[1]);
  w0[3] = cvtpk(s1[2], s1[3]);
  w1[0] = cvtpk(s2[0], s2[1]);
  w1[1] = cvtpk(s2[2], s2[3]);
  w1[2] = cvtpk(s3[0], s3[1]);
  w1[3] = cvtpk(s3[2], s3[3]);
  pf0 = __builtin_bit_cast(short8, w0);
  pf1 = __builtin_bit_cast(short8, w1);
}

__global__ __launch_bounds__(256, 4) void attn(const short* __restrict__ Qb,
                                               const short* __restrict__ Kb,
                                               const short* __restrict__ Vtb,
                                               short* __restrict__ X) {
  // [buf][K=0/V=1][4 chunks x 64 lanes x 8 shorts]
  __shared__ short KV[2][2][2048];
  const int tid = threadIdx.x;
  const int lane = tid & 63;
  const int w = tid >> 6;
  const int l15 = lane & 15, g = lane >> 4;
  const int id = blockIdx.x;       // id = qblk*64 + bh  ->  id%8 == bh%8
  const int bh = id & 63;
  const int qblk = id >> 6;        // 0..15
  const int bb = bh >> 4, hh = bh & 15;
  const int q0 = qblk * 128 + w * 32;

  const short* Qp = Qb + ((size_t)bh * 2048 + q0) * 32;
  const short* Kp = Kb + (size_t)bh * 2048 * 32;
  const short* Vp = Vtb + (size_t)bh * 32 * 2048;

  short8 qfA = *(const short8*)(Qp + l15 * 32 + g * 8);
  short8 qfB = *(const short8*)(Qp + (16 + l15) * 32 + g * 8);

  const int kbase = 8 * (l15 >> 2) + (l15 & 3);
  const int koff = (w & 1) * 4 + (w >> 1) * 32;   // chunk w: {0,4,32,36}
  const int vrow = (w >> 1) * 16;
  const int vcol = (w & 1) * 32;
  const short* Ksrc0 = Kp + (size_t)(kbase + koff) * 32 + g * 8;
  const short* Vsrc0 = Vp + (size_t)(l15 + vrow) * 2048 + vcol + g * 8;

  f32x4 zf = {0.f, 0.f, 0.f, 0.f};
  f32x4 o_loA = zf, o_hiA = zf, o_loB = zf, o_hiB = zf;
  f32x4 accLA = zf, accLB = zf;
  u32x4 ones_u = {0x3F803F80u, 0x3F803F80u, 0x3F803F80u, 0x3F803F80u};
  const short8 ones = __builtin_bit_cast(short8, ones_u);

#define STAGE(b, t0)                                                        \
  {                                                                         \
    __builtin_amdgcn_global_load_lds((gu32*)(Ksrc0 + (size_t)(t0) * 32),    \
                                     (lu32*)&KV[b][0][w * 512], 16, 0, 0);  \
    __builtin_amdgcn_global_load_lds((gu32*)(Vsrc0 + (t0)),                 \
                                     (lu32*)&KV[b][1][w * 512], 16, 0, 0);  \
  }

#define BODY(b)                                                       \
  {                                                                   \
    short8 k0 = *(const short8*)(&KV[b][0][0 * 512 + lane * 8]);      \
    short8 k1 = *(const short8*)(&KV[b][0][1 * 512 + lane * 8]);      \
    short8 k2 = *(const short8*)(&KV[b][0][2 * 512 + lane * 8]);      \
    short8 k3 = *(const short8*)(&KV[b][0][3 * 512 + lane * 8]);      \
    short8 vlo0 = *(const short8*)(&KV[b][1][0 * 512 + lane * 8]);    \
    short8 vlo1 = *(const short8*)(&KV[b][1][1 * 512 + lane * 8]);    \
    short8 vhi0 = *(const short8*)(&KV[b][1][2 * 512 + lane * 8]);    \
    short8 vhi1 = *(const short8*)(&KV[b][1][3 * 512 + lane * 8]);    \
    short8 pfA0, pfA1, pfB0, pfB1;                                    \
    qk_half(k0, k1, k2, k3, qfA, zf, pfA0, pfA1);                     \
    qk_half(k0, k1, k2, k3, qfB, zf, pfB0, pfB1);                     \
    __builtin_amdgcn_s_setprio(1);                                    \
    accLA = MFMA16(pfA0, ones, accLA);                                \
    accLA = MFMA16(pfA1, ones, accLA);                                \
    accLB = MFMA16(pfB0, ones, accLB);                                \
    accLB = MFMA16(pfB1, ones, accLB);                                \
    o_loA = MFMA16(pfA0, vlo0, o_loA);                                \
    o_loA = MFMA16(pfA1, vlo1, o_loA);                                \
    o_hiA = MFMA16(pfA0, vhi0, o_hiA);                                \
    o_hiA = MFMA16(pfA1, vhi1, o_hiA);                                \
    o_loB = MFMA16(pfB0, vlo0, o_loB);                                \
    o_loB = MFMA16(pfB1, vlo1, o_loB);                                \
    o_hiB = MFMA16(pfB0, vhi0, o_hiB);                                \
    o_hiB = MFMA16(pfB1, vhi1, o_hiB);                                \
    __builtin_amdgcn_s_setprio(0);                                    \
  }

  STAGE(0, 0);
  __syncthreads();
  for (int t0 = 0; t0 < 2048; t0 += 128) {
    STAGE(1, t0 + 64);
    BODY(0);
    __syncthreads();
    if (t0 + 128 < 2048) {
      STAGE(0, t0 + 128);
    }
    BODY(1);
    __syncthreads();
  }
#undef STAGE
#undef BODY

#pragma unroll
  for (int i = 0; i < 4; ++i) {
    float invA = 1.0f / accLA[i];
    float invB = 1.0f / accLB[i];
    int ssA = q0 + 4 * g + i;
    size_t baseA = ((size_t)bb * 2048 + ssA) * 512 + hh * 32;
    X[baseA + l15] = f2b(o_loA[i] * invA);
    X[baseA + 16 + l15] = f2b(o_hiA[i] * invA);
    size_t baseB = baseA + (size_t)16 * 512;
    X[baseB + l15] = f2b(o_loB[i] * invB);
    X[baseB + 16 + l15] = f2b(o_hiB[i] * invB);
  }
}

// ===================== launcher =====================
extern "C" void kernel_launch(void* const* d_in, const int* in_sizes, int n_in,
                              void* d_out, int out_size, void* d_ws, size_t ws_size,
                              hipStream_t stream) {
  const float* q = (const float*)d_in[0];
  const float* k = (const float*)d_in[1];
  const float* v = (const float*)d_in[2];
  const float* Wq = (const float*)d_in[3];
  const float* Wk = (const float*)d_in[4];
  const float* Wv = (const float*)d_in[5];
  const float* Wo = (const float*)d_in[6];

  char* ws = (char*)d_ws;
  const size_t MB = 1u << 20;
  short* WqT = (short*)(ws + 0 * MB);   // [512][1024] bf16  } contiguous =
  short* WkT = (short*)(ws + 1 * MB);   // [512][1024]       } BTall[1536][1024]
  short* WvT = (short*)(ws + 2 * MB);   // [512][1024]       }
  short* WoT = (short*)(ws + 3 * MB);   // [1024][512] bf16
  short* Qb  = (short*)(ws + 4 * MB);   // [64][2048][32] bf16 (8 MiB)
  short* Kb  = (short*)(ws + 12 * MB);  // [64][2048][32]
  short* Vtb = (short*)(ws + 20 * MB);  // [64][32][2048]
  short* Xb  = (short*)(ws + 28 * MB);  // [8192][512]

  prep_weights<<<8192, 256, 0, stream>>>(Wq, Wk, Wv, Wo, WqT, WkT, WvT, WoT);
  proj_gemm<<<768, 256, 0, stream>>>(q, k, v, WqT, Qb, Kb, Vtb);
  attn<<<1024, 256, 0, stream>>>(Qb, Kb, Vtb, Xb);
  out_gemm<<<512, 256, 0, stream>>>(Xb, WoT, (float*)d_out);
}